// Round 6
// baseline (144.101 us; speedup 1.0000x reference)
//
#include <hip/hip_runtime.h>
#include <stdint.h>

#define LOG2PI_F 1.8378770664093453f
#define D_DIM 1024

typedef float v4f __attribute__((ext_vector_type(4)));

// ---------- deterministic counter-based RNG (splitmix64 finalizer) ----------
__device__ __forceinline__ uint32_t mix64_32(uint64_t z) {
    z ^= z >> 33; z *= 0xff51afd7ed558ccdULL;
    z ^= z >> 33; z *= 0xc4ceb9fe1a85ec53ULL;
    z ^= z >> 33;
    return (uint32_t)z;
}
// strictly inside (0,1): [2^-24, 1-2^-24]
__device__ __forceinline__ float unif01(uint32_t stream, uint32_t idx) {
    uint32_t h = mix64_32(((uint64_t)stream << 32) | (uint64_t)idx);
    return (float)(h >> 9) * 0x1p-23f + 0x1p-24f;
}
__device__ __forceinline__ float softplusf(float r) { return log1pf(expf(r)); }

union F4 { v4f v; float f[4]; };

// =====================================================================
// Kernel A: neg_likelihood partials.  1024 blocks x 256 thr, 64 rows/block
// (16 rows/wave, 4 groups of 4).  Coefficients H=0.5/s^2, A=mu/s^2 live in
// REGISTERS (each lane owns dims k*256+lane*4, k=0..3): zero LDS reads and
// zero barriers in the setup/stream path.
// =====================================================================
__global__ __launch_bounds__(256) void hdp_lik_kernel(
    const float* __restrict__ x, const float* __restrict__ mu_c,
    const float* __restrict__ rho_c, double* __restrict__ partial)
{
    __shared__ double wpart[4];
    const int tid = threadIdx.x, wid = tid >> 6, lane = tid & 63;

    // ---- per-lane coefficient registers (16 dims each) ----
    float H0[16], A0[16], H1[16], A1[16];
    float sls0 = 0.f, sls1 = 0.f, bq0 = 0.f, bq1 = 0.f;
#pragma unroll
    for (int k = 0; k < 4; ++k) {
        const int d = k * 256 + lane * 4;
        F4 r0, r1, m0, m1;
        r0.v = *(const v4f*)(rho_c + d);
        r1.v = *(const v4f*)(rho_c + D_DIM + d);
        m0.v = *(const v4f*)(mu_c + d);
        m1.v = *(const v4f*)(mu_c + D_DIM + d);
#pragma unroll
        for (int e = 0; e < 4; ++e) {
            float s0 = softplusf(r0.f[e]);
            float i0 = 1.f / (s0 * s0);
            H0[k * 4 + e] = 0.5f * i0; A0[k * 4 + e] = m0.f[e] * i0;
            sls0 += logf(s0); bq0 += 0.5f * m0.f[e] * m0.f[e] * i0;
            float s1 = softplusf(r1.f[e]);
            float i1 = 1.f / (s1 * s1);
            H1[k * 4 + e] = 0.5f * i1; A1[k * 4 + e] = m1.f[e] * i1;
            sls1 += logf(s1); bq1 += 0.5f * m1.f[e] * m1.f[e] * i1;
        }
    }
    // wave covers all 1024 dims -> butterfly leaves totals in every lane
#pragma unroll
    for (int off = 32; off; off >>= 1) {
        sls0 += __shfl_xor(sls0, off); sls1 += __shfl_xor(sls1, off);
        bq0  += __shfl_xor(bq0,  off); bq1  += __shfl_xor(bq1,  off);
    }
    const float ent = 0.5f * 1024.f * (LOG2PI_F + 1.f) + 0.5f * (sls0 + sls1);
    const float V0 = ent - 0.5f * 1024.f * LOG2PI_F - sls0 - bq0;
    const float V1 = ent - 0.5f * 1024.f * LOG2PI_F - sls1 - bq1;

    double wsum = 0.0;
    const int rowbase = blockIdx.x * 64 + wid * 16;
#pragma unroll
    for (int g = 0; g < 4; ++g) {          // 4 groups of 4 rows per wave
        const int r0 = rowbase + g * 4;
        float q0[4] = {0.f, 0.f, 0.f, 0.f}, q1[4] = {0.f, 0.f, 0.f, 0.f};
#pragma unroll
        for (int k = 0; k < 4; ++k) {
            const int d = k * 256 + lane * 4;   // coalesced 1KB/wave-instr
#pragma unroll
            for (int r = 0; r < 4; ++r) {
                F4 xv;
                xv.v = *(const v4f*)(x + (size_t)(r0 + r) * D_DIM + d);
#pragma unroll
                for (int e = 0; e < 4; ++e) {
                    float xe = xv.f[e];
                    float xx = xe * xe;
                    q0[r] = fmaf(xx, H0[k * 4 + e], q0[r]);
                    q0[r] = fmaf(-xe, A0[k * 4 + e], q0[r]);
                    q1[r] = fmaf(xx, H1[k * 4 + e], q1[r]);
                    q1[r] = fmaf(-xe, A1[k * 4 + e], q1[r]);
                }
            }
        }
#pragma unroll
        for (int r = 0; r < 4; ++r) {
            float a = q0[r], b = q1[r];
#pragma unroll
            for (int off = 32; off; off >>= 1) { a += __shfl_xor(a, off); b += __shfl_xor(b, off); }
            const uint32_t row = (uint32_t)(r0 + r);
            // Beta(1,1)=U(0,1) stick-breaking (distributionally faithful)
            float u0 = unif01(1u, 2u * row), u1v = unif01(1u, 2u * row + 1u);
            float lp0 = logf(u0);
            float lp1 = logf(u1v) + logf(1.f - u0);
            float v0 = V0 - a, v1 = V1 - b;
            float s0 = lp0 + v0, s1 = lp1 + v1;
            float mx = fmaxf(s0, s1);
            float e0 = expf(s0 - mx), e1 = expf(s1 - mx);
            float phi0 = e0 / (e0 + e1);
            wsum += (double)(phi0 * v0 + (1.f - phi0) * v1);
        }
    }
    if (lane == 0) wpart[wid] = wsum;
    __syncthreads();
    if (tid == 0) partial[blockIdx.x] = wpart[0] + wpart[1] + wpart[2] + wpart[3];
}

// =====================================================================
// Kernel B: MC sample + classifier logits (exact R2 structure, f32 out).
// 256 blocks x 256 thr, 16 rows/block (4 waves x 4 rows).
// =====================================================================
__global__ __launch_bounds__(256) void hdp_cls_kernel(
    const float* __restrict__ mu_c, const float* __restrict__ rho_c,
    const float* __restrict__ mu_f, const float* __restrict__ rho_f,
    float* __restrict__ out)
{
    __shared__ float MU0[D_DIM], SD0[D_DIM], MU1[D_DIM], SD1[D_DIM];
    __shared__ float HF0[D_DIM], AF0[D_DIM], HF1[D_DIM], AF1[D_DIM];
    __shared__ float red[1024];
    __shared__ float CF[2];
    const int tid = threadIdx.x;

    float slsf0 = 0.f, slsf1 = 0.f, bqf0 = 0.f, bqf1 = 0.f;
    {
        const int d = tid * 4;
#pragma unroll
        for (int e = 0; e < 4; ++e) {
            MU0[d + e] = mu_c[d + e];           SD0[d + e] = softplusf(rho_c[d + e]);
            MU1[d + e] = mu_c[D_DIM + d + e];   SD1[d + e] = softplusf(rho_c[D_DIM + d + e]);
            float mf0 = mu_f[d + e], sf0 = softplusf(rho_f[d + e]);
            float i0 = 1.f / (sf0 * sf0);
            HF0[d + e] = 0.5f * i0; AF0[d + e] = mf0 * i0;
            slsf0 += logf(sf0); bqf0 += 0.5f * mf0 * mf0 * i0;
            float mf1 = mu_f[D_DIM + d + e], sf1 = softplusf(rho_f[D_DIM + d + e]);
            float i1 = 1.f / (sf1 * sf1);
            HF1[d + e] = 0.5f * i1; AF1[d + e] = mf1 * i1;
            slsf1 += logf(sf1); bqf1 += 0.5f * mf1 * mf1 * i1;
        }
    }
    red[tid] = slsf0; red[256 + tid] = slsf1; red[512 + tid] = bqf0; red[768 + tid] = bqf1;
    __syncthreads();
    for (int s = 128; s > 0; s >>= 1) {
        if (tid < s) {
            red[tid]       += red[tid + s];
            red[256 + tid] += red[256 + tid + s];
            red[512 + tid] += red[512 + tid + s];
            red[768 + tid] += red[768 + tid + s];
        }
        __syncthreads();
    }
    if (tid == 0) {
        CF[0] = -0.5f * 1024.f * LOG2PI_F - red[0]   - red[512];
        CF[1] = -0.5f * 1024.f * LOG2PI_F - red[256] - red[768];
    }
    __syncthreads();

    const int wid = tid >> 6, lane = tid & 63;
    const float CF0 = CF[0], CF1 = CF[1];
    for (int r = 0; r < 4; ++r) {
        const uint32_t j = (uint32_t)blockIdx.x * 16u + (uint32_t)wid * 4u + (uint32_t)r;
        // mixture weights + categorical draw (wave-uniform, no divergence)
        float b0 = unif01(2u, 2u * j), b1 = unif01(2u, 2u * j + 1u);
        float wn0 = b0 / (b0 + b1 * (1.f - b0));
        int dr = (unif01(3u, j) < wn0) ? 0 : 1;
        float bi0 = unif01(5u, 2u * j), bi1 = unif01(5u, 2u * j + 1u);
        float pi0 = bi0, pi1 = bi1 * (1.f - bi0);
        const float* MU = dr ? &MU1[0] : &MU0[0];
        const float* SD = dr ? &SD1[0] : &SD0[0];
        float qf0 = 0.f, qf1 = 0.f;
#pragma unroll
        for (int k = 0; k < 4; ++k) {
            const int dd = k * 256 + lane * 4;
            F4 mu, sd, h0, a0, h1, a1;
            mu.v = *(const v4f*)&MU[dd];
            sd.v = *(const v4f*)&SD[dd];
            h0.v = *(const v4f*)&HF0[dd];
            a0.v = *(const v4f*)&AF0[dd];
            h1.v = *(const v4f*)&HF1[dd];
            a1.v = *(const v4f*)&AF1[dd];
#pragma unroll
            for (int e = 0; e < 4; e += 2) {
                // Box-Muller pair for dims (dd+e, dd+e+1)
                uint32_t p = j * 512u + (uint32_t)((dd + e) >> 1);
                float uu1 = unif01(4u, p), uu2 = unif01(6u, p);
                float rad = sqrtf(-2.f * logf(uu1));
                float sn, cs;
                __sincosf(6.283185307179586f * uu2, &sn, &cs);
                float mc0 = fmaf(sd.f[e],     rad * cs, mu.f[e]);
                float mc1 = fmaf(sd.f[e + 1], rad * sn, mu.f[e + 1]);
                float xx0 = mc0 * mc0, xx1 = mc1 * mc1;
                qf0 = fmaf(xx0, h0.f[e], qf0);      qf0 = fmaf(-mc0, a0.f[e], qf0);
                qf0 = fmaf(xx1, h0.f[e + 1], qf0);  qf0 = fmaf(-mc1, a0.f[e + 1], qf0);
                qf1 = fmaf(xx0, h1.f[e], qf1);      qf1 = fmaf(-mc0, a1.f[e], qf1);
                qf1 = fmaf(xx1, h1.f[e + 1], qf1);  qf1 = fmaf(-mc1, a1.f[e + 1], qf1);
            }
        }
#pragma unroll
        for (int off = 32; off; off >>= 1) { qf0 += __shfl_xor(qf0, off); qf1 += __shfl_xor(qf1, off); }
        float lp0 = CF0 - qf0, lp1 = CF1 - qf1;
        float mx = fmaxf(lp0, lp1);
        float e0 = expf(lp0 - mx), e1 = expf(lp1 - mx);
        float inv = 1.f / (e0 + e1);
        if (lane == 0) {
            out[2u * j]      = pi0 * e0 * inv;
            out[2u * j + 1u] = pi1 * e1 * inv;
        }
    }
}

// =====================================================================
// Kernel C: deterministic final reduce of 1024 f64 partials -> out[8192]
// =====================================================================
__global__ void hdp_final_kernel(const double* __restrict__ partial,
                                 float* __restrict__ out)
{
    const int lane = threadIdx.x;  // 64 threads
    double s = 0.0;
    for (int i = lane; i < 1024; i += 64) s += partial[i];
#pragma unroll
    for (int off = 32; off; off >>= 1) s += __shfl_xor(s, off);
    if (lane == 0) out[8192] = (float)(-s / 65536.0);
}

extern "C" void kernel_launch(void* const* d_in, const int* in_sizes, int n_in,
                              void* d_out, int out_size, void* d_ws, size_t ws_size,
                              hipStream_t stream) {
    const float* x     = (const float*)d_in[0];
    const float* mu_c  = (const float*)d_in[1];
    const float* rho_c = (const float*)d_in[2];
    const float* mu_f  = (const float*)d_in[3];
    const float* rho_f = (const float*)d_in[4];
    float* out = (float*)d_out;        // 8192 logits + 1 scalar, f32
    double* partial = (double*)d_ws;   // 1024 doubles = 8 KB scratch

    hipLaunchKernelGGL(hdp_lik_kernel, dim3(1024), dim3(256), 0, stream,
                       x, mu_c, rho_c, partial);
    hipLaunchKernelGGL(hdp_cls_kernel, dim3(256), dim3(256), 0, stream,
                       mu_c, rho_c, mu_f, rho_f, out);
    hipLaunchKernelGGL(hdp_final_kernel, dim3(1), dim3(64), 0, stream,
                       partial, out);
}

// Round 7
// 65.216 us; speedup vs baseline: 2.2096x; 2.2096x over previous
//
#include <hip/hip_runtime.h>
#include <stdint.h>

#define LOG2PI_F 1.8378770664093453f
#define D_DIM 1024

typedef float v4f __attribute__((ext_vector_type(4)));

// ---------- deterministic counter-based RNG (splitmix64 finalizer) ----------
__device__ __forceinline__ uint32_t mix64_32(uint64_t z) {
    z ^= z >> 33; z *= 0xff51afd7ed558ccdULL;
    z ^= z >> 33; z *= 0xc4ceb9fe1a85ec53ULL;
    z ^= z >> 33;
    return (uint32_t)z;
}
// strictly inside (0,1): [2^-24, 1-2^-24]
__device__ __forceinline__ float unif01(uint32_t stream, uint32_t idx) {
    uint32_t h = mix64_32(((uint64_t)stream << 32) | (uint64_t)idx);
    return (float)(h >> 9) * 0x1p-23f + 0x1p-24f;
}
__device__ __forceinline__ float softplusf(float r) { return log1pf(expf(r)); }

union F4 { v4f v; float f[4]; };

// =====================================================================
// Kernel A: neg_likelihood partial sums.  1024 blocks x 256 thr,
// 64 rows/block (4 waves x 16 rows), coefficients staged once in LDS.
// BYTE-IDENTICAL to the proven 70.35us R2 version.
// =====================================================================
__global__ __launch_bounds__(256) void hdp_lik_kernel(
    const float* __restrict__ x, const float* __restrict__ mu_c,
    const float* __restrict__ rho_c, double* __restrict__ partial)
{
    __shared__ float H0[D_DIM], A0[D_DIM], H1[D_DIM], A1[D_DIM];
    __shared__ float red[1024];
    __shared__ float Vb[2];
    __shared__ double wpart[4];
    const int tid = threadIdx.x;

    // ---- per-component coefficients: H = 0.5/sigma^2, A = mu/sigma^2 ----
    float sls0 = 0.f, sls1 = 0.f, bq0 = 0.f, bq1 = 0.f;
    {
        const int d = tid * 4;
        F4 r0, r1, m0, m1;
        r0.v = *(const v4f*)(rho_c + d);
        r1.v = *(const v4f*)(rho_c + D_DIM + d);
        m0.v = *(const v4f*)(mu_c + d);
        m1.v = *(const v4f*)(mu_c + D_DIM + d);
#pragma unroll
        for (int e = 0; e < 4; ++e) {
            float s0 = softplusf(r0.f[e]);
            float i0 = 1.f / (s0 * s0);
            H0[d + e] = 0.5f * i0; A0[d + e] = m0.f[e] * i0;
            sls0 += logf(s0); bq0 += 0.5f * m0.f[e] * m0.f[e] * i0;
            float s1 = softplusf(r1.f[e]);
            float i1 = 1.f / (s1 * s1);
            H1[d + e] = 0.5f * i1; A1[d + e] = m1.f[e] * i1;
            sls1 += logf(s1); bq1 += 0.5f * m1.f[e] * m1.f[e] * i1;
        }
    }
    red[tid] = sls0; red[256 + tid] = sls1; red[512 + tid] = bq0; red[768 + tid] = bq1;
    __syncthreads();
    for (int s = 128; s > 0; s >>= 1) {   // deterministic tree reduce
        if (tid < s) {
            red[tid]       += red[tid + s];
            red[256 + tid] += red[256 + tid + s];
            red[512 + tid] += red[512 + tid + s];
            red[768 + tid] += red[768 + tid + s];
        }
        __syncthreads();
    }
    if (tid == 0) {
        float SLS0 = red[0], SLS1 = red[256], BQ0 = red[512], BQ1 = red[768];
        float ent = 0.5f * 1024.f * (LOG2PI_F + 1.f) + 0.5f * (SLS0 + SLS1);
        // v_t(row) = ent + const_t - quad_t = Vb[t] - (sum_d xx*H_t - x*A_t)
        Vb[0] = ent - 0.5f * 1024.f * LOG2PI_F - SLS0 - BQ0;
        Vb[1] = ent - 0.5f * 1024.f * LOG2PI_F - SLS1 - BQ1;
    }
    __syncthreads();

    const int wid = tid >> 6, lane = tid & 63;
    const float V0 = Vb[0], V1 = Vb[1];
    double wsum = 0.0;
    const int rowbase = blockIdx.x * 64 + wid * 16;
    for (int g = 0; g < 4; ++g) {          // 4 groups of 4 rows (coef reads amortized 4x)
        const int r0 = rowbase + g * 4;
        float q0[4] = {0.f, 0.f, 0.f, 0.f}, q1[4] = {0.f, 0.f, 0.f, 0.f};
#pragma unroll
        for (int k = 0; k < 4; ++k) {
            const int d = k * 256 + lane * 4;          // coalesced: lane i -> consecutive 16B
            F4 h0, a0v, h1, a1v;
            h0.v  = *(const v4f*)&H0[d];
            a0v.v = *(const v4f*)&A0[d];
            h1.v  = *(const v4f*)&H1[d];
            a1v.v = *(const v4f*)&A1[d];
#pragma unroll
            for (int r = 0; r < 4; ++r) {
                F4 xv; xv.v = *(const v4f*)(x + (size_t)(r0 + r) * D_DIM + d);
#pragma unroll
                for (int e = 0; e < 4; ++e) {
                    float xe = xv.f[e];
                    float xx = xe * xe;
                    q0[r] = fmaf(xx, h0.f[e], q0[r]);  q0[r] = fmaf(-xe, a0v.f[e], q0[r]);
                    q1[r] = fmaf(xx, h1.f[e], q1[r]);  q1[r] = fmaf(-xe, a1v.f[e], q1[r]);
                }
            }
        }
#pragma unroll
        for (int r = 0; r < 4; ++r) {
            float a = q0[r], b = q1[r];
#pragma unroll
            for (int off = 32; off; off >>= 1) { a += __shfl_xor(a, off); b += __shfl_xor(b, off); }
            const uint32_t row = (uint32_t)(r0 + r);
            // Beta(1,1) = U(0,1) stick-breaking weights (distributionally faithful)
            float u0 = unif01(1u, 2u * row), u1v = unif01(1u, 2u * row + 1u);
            float lp0 = logf(u0);
            float lp1 = logf(u1v) + logf(1.f - u0);
            float v0 = V0 - a, v1 = V1 - b;
            float s0 = lp0 + v0, s1 = lp1 + v1;
            float mx = fmaxf(s0, s1);
            float e0 = expf(s0 - mx), e1 = expf(s1 - mx);
            float phi0 = e0 / (e0 + e1);
            wsum += (double)(phi0 * v0 + (1.f - phi0) * v1);   // sum_t phi_t*(ent+log_pdf_t)
        }
    }
    if (lane == 0) wpart[wid] = wsum;
    __syncthreads();
    if (tid == 0) partial[blockIdx.x] = wpart[0] + wpart[1] + wpart[2] + wpart[3];
}

// =====================================================================
// Kernel B: MC sample + classifier logits + (block 256) final reduce.
// Grid 257 x 256 thr.  Blocks 0..255: 16 MC rows each (4 waves x 4 rows),
// setup via wave-shuffle + 1 barrier.  Block 256: reduce A's partials.
// =====================================================================
__global__ __launch_bounds__(256) void hdp_cls_kernel(
    const float* __restrict__ mu_c, const float* __restrict__ rho_c,
    const float* __restrict__ mu_f, const float* __restrict__ rho_f,
    const double* __restrict__ partial, float* __restrict__ out)
{
    const int tid = threadIdx.x, wid = tid >> 6, lane = tid & 63;

    if (blockIdx.x == 256) {
        // ---- final deterministic reduce (was kernel C) ----
        if (wid == 0) {
            double s = 0.0;
            for (int i = lane; i < 1024; i += 64) s += partial[i];
#pragma unroll
            for (int off = 32; off; off >>= 1) s += __shfl_xor(s, off);
            if (lane == 0) out[8192] = (float)(-s / 65536.0);
        }
        return;
    }

    __shared__ float MU0[D_DIM], SD0[D_DIM], MU1[D_DIM], SD1[D_DIM];
    __shared__ float HF0[D_DIM], AF0[D_DIM], HF1[D_DIM], AF1[D_DIM];
    __shared__ float wred[4][2];

    float cf0 = 0.f, cf1 = 0.f;   // accumulates -(log sf + 0.5 mf^2/sf^2)
    {
        const int d = tid * 4;
#pragma unroll
        for (int e = 0; e < 4; ++e) {
            MU0[d + e] = mu_c[d + e];           SD0[d + e] = softplusf(rho_c[d + e]);
            MU1[d + e] = mu_c[D_DIM + d + e];   SD1[d + e] = softplusf(rho_c[D_DIM + d + e]);
            float mf0 = mu_f[d + e], sf0 = softplusf(rho_f[d + e]);
            float i0 = 1.f / (sf0 * sf0);
            HF0[d + e] = 0.5f * i0; AF0[d + e] = mf0 * i0;
            cf0 -= logf(sf0) + 0.5f * mf0 * mf0 * i0;
            float mf1 = mu_f[D_DIM + d + e], sf1 = softplusf(rho_f[D_DIM + d + e]);
            float i1 = 1.f / (sf1 * sf1);
            HF1[d + e] = 0.5f * i1; AF1[d + e] = mf1 * i1;
            cf1 -= logf(sf1) + 0.5f * mf1 * mf1 * i1;
        }
    }
#pragma unroll
    for (int off = 32; off; off >>= 1) {
        cf0 += __shfl_xor(cf0, off); cf1 += __shfl_xor(cf1, off);
    }
    if (lane == 0) { wred[wid][0] = cf0; wred[wid][1] = cf1; }
    __syncthreads();
    const float CF0 = -0.5f * 1024.f * LOG2PI_F
                    + wred[0][0] + wred[1][0] + wred[2][0] + wred[3][0];
    const float CF1 = -0.5f * 1024.f * LOG2PI_F
                    + wred[0][1] + wred[1][1] + wred[2][1] + wred[3][1];

    for (int r = 0; r < 4; ++r) {
        const uint32_t j = (uint32_t)blockIdx.x * 16u + (uint32_t)wid * 4u + (uint32_t)r;
        // mixture weights + categorical draw (wave-uniform, no divergence)
        float b0 = unif01(2u, 2u * j), b1 = unif01(2u, 2u * j + 1u);
        float wn0 = b0 / (b0 + b1 * (1.f - b0));
        int dr = (unif01(3u, j) < wn0) ? 0 : 1;
        float bi0 = unif01(5u, 2u * j), bi1 = unif01(5u, 2u * j + 1u);
        float pi0 = bi0, pi1 = bi1 * (1.f - bi0);
        const float* MU = dr ? &MU1[0] : &MU0[0];
        const float* SD = dr ? &SD1[0] : &SD0[0];
        float qf0 = 0.f, qf1 = 0.f;
#pragma unroll
        for (int k = 0; k < 4; ++k) {
            const int dd = k * 256 + lane * 4;
            F4 mu, sd, h0, a0, h1, a1;
            mu.v = *(const v4f*)&MU[dd];
            sd.v = *(const v4f*)&SD[dd];
            h0.v = *(const v4f*)&HF0[dd];
            a0.v = *(const v4f*)&AF0[dd];
            h1.v = *(const v4f*)&HF1[dd];
            a1.v = *(const v4f*)&AF1[dd];
#pragma unroll
            for (int e = 0; e < 4; e += 2) {
                // Box-Muller pair for dims (dd+e, dd+e+1)
                uint32_t p = j * 512u + (uint32_t)((dd + e) >> 1);
                float uu1 = unif01(4u, p), uu2 = unif01(6u, p);
                float rad = sqrtf(-2.f * logf(uu1));
                float sn, cs;
                __sincosf(6.283185307179586f * uu2, &sn, &cs);
                float mc0 = fmaf(sd.f[e],     rad * cs, mu.f[e]);
                float mc1 = fmaf(sd.f[e + 1], rad * sn, mu.f[e + 1]);
                float xx0 = mc0 * mc0, xx1 = mc1 * mc1;
                qf0 = fmaf(xx0, h0.f[e], qf0);      qf0 = fmaf(-mc0, a0.f[e], qf0);
                qf0 = fmaf(xx1, h0.f[e + 1], qf0);  qf0 = fmaf(-mc1, a0.f[e + 1], qf0);
                qf1 = fmaf(xx0, h1.f[e], qf1);      qf1 = fmaf(-mc0, a1.f[e], qf1);
                qf1 = fmaf(xx1, h1.f[e + 1], qf1);  qf1 = fmaf(-mc1, a1.f[e + 1], qf1);
            }
        }
#pragma unroll
        for (int off = 32; off; off >>= 1) { qf0 += __shfl_xor(qf0, off); qf1 += __shfl_xor(qf1, off); }
        float lp0 = CF0 - qf0, lp1 = CF1 - qf1;
        float mx = fmaxf(lp0, lp1);
        float e0 = expf(lp0 - mx), e1 = expf(lp1 - mx);
        float inv = 1.f / (e0 + e1);
        if (lane == 0) {
            out[2u * j]      = pi0 * e0 * inv;
            out[2u * j + 1u] = pi1 * e1 * inv;
        }
    }
}

extern "C" void kernel_launch(void* const* d_in, const int* in_sizes, int n_in,
                              void* d_out, int out_size, void* d_ws, size_t ws_size,
                              hipStream_t stream) {
    const float* x     = (const float*)d_in[0];
    const float* mu_c  = (const float*)d_in[1];
    const float* rho_c = (const float*)d_in[2];
    const float* mu_f  = (const float*)d_in[3];
    const float* rho_f = (const float*)d_in[4];
    float* out = (float*)d_out;        // 8192 logits + 1 scalar, f32
    double* partial = (double*)d_ws;   // 1024 doubles = 8 KB scratch

    hipLaunchKernelGGL(hdp_lik_kernel, dim3(1024), dim3(256), 0, stream,
                       x, mu_c, rho_c, partial);
    hipLaunchKernelGGL(hdp_cls_kernel, dim3(257), dim3(256), 0, stream,
                       mu_c, rho_c, mu_f, rho_f, partial, out);
}